// Round 15
// baseline (151.693 us; speedup 1.0000x reference)
//
#include <hip/hip_runtime.h>
#include <math.h>

#define RS2f 0.70710678118654752f
#define XSTR 4160   // padded row stride (shorts): 8320 B = 32.5 x 256 B
                    // breaks power-of-2 channel aliasing on row-strided reads

typedef __attribute__((ext_vector_type(8))) short bf16x8;
typedef __attribute__((ext_vector_type(4))) float f32x4;

__device__ __forceinline__ unsigned short f2bf(float f) {
    unsigned u = __float_as_uint(f);
    unsigned r = (u + 0x7fffu + ((u >> 16) & 1u)) >> 16;   // RNE
    return (unsigned short)r;
}
__device__ __forceinline__ float bf2f(unsigned short h) {
    return __uint_as_float(((unsigned)h) << 16);
}

// ==================================================================
// Fused convert: x (1024x2048) and W (512x2048) fp32 -> bf16 hi/lo
// concat along K, padded row stride XSTR.
// ==================================================================
__global__ __launch_bounds__(256) void split_all(const float* __restrict__ x,
                                                 const float* __restrict__ W,
                                                 unsigned short* __restrict__ xc,
                                                 unsigned short* __restrict__ wc) {
    int idx = blockIdx.x * 256 + threadIdx.x;      // 786432 total
    const float* src; unsigned short* dst;
    if (idx < 524288) { src = x; dst = xc; }
    else              { idx -= 524288; src = W; dst = wc; }
    int m = idx >> 9;
    int c4 = (idx & 511) << 2;
    const float4 v = *(const float4*)&src[m * 2048 + c4];
    ushort4 hi, lo;
    hi.x = f2bf(v.x); lo.x = f2bf(v.x - bf2f(hi.x));
    hi.y = f2bf(v.y); lo.y = f2bf(v.y - bf2f(hi.y));
    hi.z = f2bf(v.z); lo.z = f2bf(v.z - bf2f(hi.z));
    hi.w = f2bf(v.w); lo.w = f2bf(v.w - bf2f(hi.w));
    *(ushort4*)&dst[(size_t)m * XSTR + c4] = hi;
    *(ushort4*)&dst[(size_t)m * XSTR + 2048 + c4] = lo;
}

// ==================================================================
// MFMA GEMM partials (R13/R14 structure: 64x64 tile, BK=64, 4 waves,
// global_load_lds width=16 staging, XOR segment swizzle, XSTR rows).
// Grid (16,8,SK).
// ==================================================================
__global__ __launch_bounds__(256) void gemm64(const unsigned short* __restrict__ A,
                                              const unsigned short* __restrict__ B,
                                              float* __restrict__ P, int nch) {
    __shared__ short As[64 * 64];        // 8 KB, unpadded (XOR swizzle)
    __shared__ short Bs[64 * 64];        // 8 KB
    const int tid = threadIdx.x, lane = tid & 63, wv = tid >> 6;
    const int quad = lane >> 4, mrow = lane & 15;
    const int m0 = blockIdx.x * 64, n0 = blockIdx.y * 64;
    const int kb = blockIdx.z * nch * 64;
    const int lrow = lane >> 3;                 // 0..7 row within group
    const int gseg = (lane & 7) ^ lrow;         // swizzled global segment

    f32x4 acc[4];
    #pragma unroll
    for (int j = 0; j < 4; ++j) acc[j] = (f32x4){0.f, 0.f, 0.f, 0.f};

    for (int ch = 0; ch < nch; ++ch) {
        const int ko = kb + ch * 64;
        #pragma unroll
        for (int t = 0; t < 2; ++t) {           // 2 row-groups of 8 per wave
            const int ra = (wv * 2 + t) * 8;
            const unsigned short* ga = A + (size_t)(m0 + ra + lrow) * XSTR + ko + gseg * 8;
            const unsigned short* gb = B + (size_t)(n0 + ra + lrow) * XSTR + ko + gseg * 8;
            __builtin_amdgcn_global_load_lds(
                (const __attribute__((address_space(1))) void*)ga,
                (__attribute__((address_space(3))) void*)(As + ra * 64), 16, 0, 0);
            __builtin_amdgcn_global_load_lds(
                (const __attribute__((address_space(1))) void*)gb,
                (__attribute__((address_space(3))) void*)(Bs + ra * 64), 16, 0, 0);
        }
        __syncthreads();
        #pragma unroll
        for (int ks = 0; ks < 2; ++ks) {
            const int q = ks * 4 + quad;        // k-segment 0..7
            const int am = wv * 16 + mrow;
            bf16x8 af = *(const bf16x8*)&As[am * 64 + ((q ^ (am & 7)) << 3)];
            #pragma unroll
            for (int j = 0; j < 4; ++j) {
                const int bn = j * 16 + mrow;
                bf16x8 bf = *(const bf16x8*)&Bs[bn * 64 + ((q ^ (bn & 7)) << 3)];
                acc[j] = __builtin_amdgcn_mfma_f32_16x16x32_bf16(af, bf, acc[j], 0, 0, 0);
            }
        }
        __syncthreads();
    }
    // C/D layout: col = lane&15, row = quad*4 + r
    float* Pz = P + (size_t)blockIdx.z * 524288;
    #pragma unroll
    for (int j = 0; j < 4; ++j)
        #pragma unroll
        for (int r = 0; r < 4; ++r)
            Pz[(m0 + wv * 16 + quad * 4 + r) * 512 + n0 + j * 16 + mrow] = acc[j][r];
}

// ==================================================================
// reduce partials + bias -> slab 0 (in-place safe: each thread owns i)
// ==================================================================
__global__ __launch_bounds__(256) void reduce_kernel(float* __restrict__ P,
                                                     const float* __restrict__ bias,
                                                     int SK) {
    int i = blockIdx.x * 256 + threadIdx.x;        // 512K total
    float s = bias[i & 511];
    for (int z = 0; z < SK; ++z) s += P[(size_t)z * 524288 + i];
    P[i] = s;
}

// ==================================================================
// Fallback fp32 GEMM (small ws): raw product to P; reduce adds bias.
// ==================================================================
__global__ __launch_bounds__(256) void gemm_f32(const float* __restrict__ A,
                                                const float* __restrict__ W,
                                                float* __restrict__ C) {
    __shared__ float Asf[64][33];
    __shared__ float Bsf[32][33];
    const int tid = threadIdx.x;
    const int m0 = blockIdx.x * 64;
    const int n0 = blockIdx.y * 32;
    const int tm = tid >> 4, tn = tid & 15;
    float acc[4][2] = {};
    for (int k0 = 0; k0 < 2048; k0 += 32) {
        #pragma unroll
        for (int i = 0; i < 8; ++i) {
            int idx = tid + i * 256;
            Asf[idx >> 5][idx & 31] = A[(m0 + (idx >> 5)) * 2048 + k0 + (idx & 31)];
        }
        #pragma unroll
        for (int i = 0; i < 4; ++i) {
            int idx = tid + i * 256;
            Bsf[idx >> 5][idx & 31] = W[(n0 + (idx >> 5)) * 2048 + k0 + (idx & 31)];
        }
        __syncthreads();
        #pragma unroll
        for (int kk = 0; kk < 32; ++kk) {
            float a0 = Asf[tm*4+0][kk], a1 = Asf[tm*4+1][kk];
            float a2 = Asf[tm*4+2][kk], a3 = Asf[tm*4+3][kk];
            float b0 = Bsf[tn*2+0][kk], b1 = Bsf[tn*2+1][kk];
            acc[0][0] += a0*b0; acc[0][1] += a0*b1;
            acc[1][0] += a1*b0; acc[1][1] += a1*b1;
            acc[2][0] += a2*b0; acc[2][1] += a2*b1;
            acc[3][0] += a3*b0; acc[3][1] += a3*b1;
        }
        __syncthreads();
    }
    #pragma unroll
    for (int r = 0; r < 4; ++r)
        #pragma unroll
        for (int c = 0; c < 2; ++c)
            C[(m0 + tm*4 + r) * 512 + n0 + tn*2 + c] = acc[r][c];
}

// ==================== circuit helpers (R5/R8/R12 structure, 77-78us measured) ====================
struct CMat { float m00r,m00i,m01r,m01i,m10r,m10i,m11r,m11i; };

__device__ __forceinline__ CMat mk_rot(const float* __restrict__ qp, int l, int w) {
    const float* g = qp + (l * 12 + w) * 3;
    float phi = g[0], th = g[1], om = g[2];
    float st, ct, sa, ca, sb, cb;
    sincosf(0.5f * th, &st, &ct);
    sincosf(0.5f * (phi + om), &sa, &ca);
    sincosf(0.5f * (phi - om), &sb, &cb);
    CMat M;
    M.m00r =  ct * ca; M.m00i = -ct * sa;
    M.m01r = -st * cb; M.m01i = -st * sb;
    M.m10r =  st * cb; M.m10i = -st * sb;
    M.m11r =  ct * ca; M.m11i =  ct * sa;
    return M;
}

template<int W> struct WI {
    static constexpr int kind = (W == 0 || W == 7) ? 2 : ((W >= 1 && W <= 6) ? 1 : 0);
    static constexpr int eb   = (W >= 8) ? (11 - W) : 0;
    static constexpr int lm   = (W >= 1 && W <= 6) ? (1 << (6 - W)) : 0;
    static constexpr int vm   = (W == 0) ? 2 : ((W == 7) ? 1 : 0);
};

__device__ __forceinline__ void exch_put(float* xbuf, int slot,
                                         const float vr[16], const float vi[16]) {
    __syncthreads();
    float4* p = (float4*)xbuf;
    #pragma unroll
    for (int j = 0; j < 8; ++j)
        p[(j << 8) + slot] = make_float4(vr[2*j], vi[2*j], vr[2*j+1], vi[2*j+1]);
    __syncthreads();
}

__device__ __forceinline__ void shfl_perm(float vr[16], float vi[16], int src) {
    #pragma unroll
    for (int e = 0; e < 16; ++e) {
        vr[e] = __shfl(vr[e], src, 64);
        vi[e] = __shfl(vi[e], src, 64);
    }
}

template<int EB>
__device__ __forceinline__ void rot_local(float vr[16], float vi[16], const CMat& M) {
    #pragma unroll
    for (int e = 0; e < 16; ++e) if (!(e & (1 << EB))) {
        const int e1 = e | (1 << EB);
        float x0r = vr[e],  x0i = vi[e];
        float x1r = vr[e1], x1i = vi[e1];
        vr[e]  = M.m00r*x0r - M.m00i*x0i + M.m01r*x1r - M.m01i*x1i;
        vi[e]  = M.m00r*x0i + M.m00i*x0r + M.m01r*x1i + M.m01i*x1r;
        vr[e1] = M.m10r*x0r - M.m10i*x0i + M.m11r*x1r - M.m11i*x1i;
        vi[e1] = M.m10r*x0i + M.m10i*x0r + M.m11r*x1i + M.m11i*x1r;
    }
}

template<int LM>
__device__ __forceinline__ void rot_lane(float vr[16], float vi[16], int lane, const CMat& M) {
    const bool hi = lane & LM;
    const float Ar = hi ? M.m11r : M.m00r, Ai = hi ? M.m11i : M.m00i;
    const float Br = hi ? M.m10r : M.m01r, Bi = hi ? M.m10i : M.m01i;
    #pragma unroll
    for (int e = 0; e < 16; ++e) {
        float pr = __shfl_xor(vr[e], LM, 64);
        float pi = __shfl_xor(vi[e], LM, 64);
        float orr = vr[e], oi = vi[e];
        vr[e] = Ar*orr - Ai*oi + Br*pr - Bi*pi;
        vi[e] = Ar*oi + Ai*orr + Br*pi + Bi*pr;
    }
}

template<int VM>
__device__ __forceinline__ void rot_wave(float vr[16], float vi[16], float* xbuf,
                                         int waveId, int lane, const CMat& M) {
    exch_put(xbuf, (waveId << 6) + lane, vr, vi);
    const float4* p = (const float4*)xbuf;
    const int ps = ((waveId ^ VM) << 6) + lane;
    const bool hi = waveId & VM;
    const float Ar = hi ? M.m11r : M.m00r, Ai = hi ? M.m11i : M.m00i;
    const float Br = hi ? M.m10r : M.m01r, Bi = hi ? M.m10i : M.m01i;
    #pragma unroll
    for (int j = 0; j < 8; ++j) {
        float4 q = p[(j << 8) + ps];
        const int e0 = 2*j, e1 = 2*j + 1;
        float r0 = vr[e0], i0 = vi[e0], r1 = vr[e1], i1 = vi[e1];
        vr[e0] = Ar*r0 - Ai*i0 + Br*q.x - Bi*q.y;
        vi[e0] = Ar*i0 + Ai*r0 + Br*q.y + Bi*q.x;
        vr[e1] = Ar*r1 - Ai*i1 + Br*q.z - Bi*q.w;
        vi[e1] = Ar*i1 + Ai*r1 + Br*q.w + Bi*q.z;
    }
}

template<int W>
__device__ __forceinline__ void rot_wire(float vr[16], float vi[16], float* xbuf,
                                         int waveId, int lane, const CMat& M) {
    if constexpr (WI<W>::kind == 0)      rot_local<WI<W>::eb>(vr, vi, M);
    else if constexpr (WI<W>::kind == 1) rot_lane<WI<W>::lm>(vr, vi, lane, M);
    else                                 rot_wave<WI<W>::vm>(vr, vi, xbuf, waveId, lane, M);
}

template<int C, int T>
__device__ __forceinline__ void cnot(float vr[16], float vi[16], float* xbuf,
                                     int waveId, int lane) {
    constexpr int ck = WI<C>::kind, tk = WI<T>::kind;
    if constexpr (ck == 0 && tk == 0) {
        constexpr int cb = 1 << WI<C>::eb, tb = 1 << WI<T>::eb;
        #pragma unroll
        for (int e = 0; e < 16; ++e) if ((e & cb) && !(e & tb)) {
            const int e1 = e | tb;
            float t = vr[e]; vr[e] = vr[e1]; vr[e1] = t;
            t = vi[e]; vi[e] = vi[e1]; vi[e1] = t;
        }
    } else if constexpr (ck == 0 && tk == 1) {
        constexpr int cb = 1 << WI<C>::eb, tm = WI<T>::lm;
        #pragma unroll
        for (int e = 0; e < 16; ++e) if (e & cb) {
            vr[e] = __shfl_xor(vr[e], tm, 64);
            vi[e] = __shfl_xor(vi[e], tm, 64);
        }
    } else if constexpr (ck == 0 && tk == 2) {
        constexpr int cb = 1 << WI<C>::eb, vm = WI<T>::vm;
        exch_put(xbuf, (waveId << 6) + lane, vr, vi);
        const float4* p = (const float4*)xbuf;
        const int ps = ((waveId ^ vm) << 6) + lane;
        #pragma unroll
        for (int j = 0; j < 8; ++j) {
            if ((((2*j) & cb) != 0) || (((2*j+1) & cb) != 0)) {
                float4 q = p[(j << 8) + ps];
                if (((2*j) & cb) != 0)   { vr[2*j]   = q.x; vi[2*j]   = q.y; }
                if (((2*j+1) & cb) != 0) { vr[2*j+1] = q.z; vi[2*j+1] = q.w; }
            }
        }
    } else if constexpr (ck == 1 && tk == 0) {
        constexpr int cm = WI<C>::lm, tb = 1 << WI<T>::eb;
        const bool cc = lane & cm;
        #pragma unroll
        for (int e = 0; e < 16; ++e) if (!(e & tb)) {
            const int e1 = e | tb;
            float a = vr[e], bb = vr[e1];
            vr[e] = cc ? bb : a; vr[e1] = cc ? a : bb;
            a = vi[e]; bb = vi[e1];
            vi[e] = cc ? bb : a; vi[e1] = cc ? a : bb;
        }
    } else if constexpr (ck == 1 && tk == 1) {
        constexpr int cm = WI<C>::lm, tm = WI<T>::lm;
        const int src = (lane & cm) ? (lane ^ tm) : lane;
        shfl_perm(vr, vi, src);
    } else if constexpr (ck == 1 && tk == 2) {
        constexpr int cm = WI<C>::lm, vm = WI<T>::vm;
        exch_put(xbuf, (waveId << 6) + lane, vr, vi);
        const float4* p = (const float4*)xbuf;
        const int ps = ((waveId ^ vm) << 6) + lane;
        const bool take = lane & cm;
        #pragma unroll
        for (int j = 0; j < 8; ++j) {
            float4 q = p[(j << 8) + ps];
            vr[2*j]   = take ? q.x : vr[2*j];   vi[2*j]   = take ? q.y : vi[2*j];
            vr[2*j+1] = take ? q.z : vr[2*j+1]; vi[2*j+1] = take ? q.w : vi[2*j+1];
        }
    } else if constexpr (ck == 2 && tk == 0) {
        constexpr int vm = WI<C>::vm, tb = 1 << WI<T>::eb;
        if (waveId & vm) {
            #pragma unroll
            for (int e = 0; e < 16; ++e) if (!(e & tb)) {
                const int e1 = e | tb;
                float t = vr[e]; vr[e] = vr[e1]; vr[e1] = t;
                t = vi[e]; vi[e] = vi[e1]; vi[e1] = t;
            }
        }
    } else {
        constexpr int vm = WI<C>::vm, tm = WI<T>::lm;
        if (waveId & vm) {
            #pragma unroll
            for (int e = 0; e < 16; ++e) {
                vr[e] = __shfl_xor(vr[e], tm, 64);
                vi[e] = __shfl_xor(vi[e], tm, 64);
            }
        }
    }
}

template<int W>
__device__ __forceinline__ void h_wire(float vr[16], float vi[16], float* xbuf,
                                       int waveId, int lane) {
    if constexpr (WI<W>::kind == 0) {
        constexpr int tb = 1 << WI<W>::eb;
        #pragma unroll
        for (int e = 0; e < 16; ++e) if (!(e & tb)) {
            const int e1 = e | tb;
            float x0 = vr[e], x1 = vr[e1];
            vr[e] = (x0 + x1) * RS2f; vr[e1] = (x0 - x1) * RS2f;
            x0 = vi[e]; x1 = vi[e1];
            vi[e] = (x0 + x1) * RS2f; vi[e1] = (x0 - x1) * RS2f;
        }
    } else if constexpr (WI<W>::kind == 1) {
        constexpr int m = WI<W>::lm;
        const float sgn = (lane & m) ? -RS2f : RS2f;
        #pragma unroll
        for (int e = 0; e < 16; ++e) {
            float pr = __shfl_xor(vr[e], m, 64);
            float pi = __shfl_xor(vi[e], m, 64);
            vr[e] = pr * RS2f + vr[e] * sgn;
            vi[e] = pi * RS2f + vi[e] * sgn;
        }
    } else {
        constexpr int vm = WI<W>::vm;
        exch_put(xbuf, (waveId << 6) + lane, vr, vi);
        const float4* p = (const float4*)xbuf;
        const int ps = ((waveId ^ vm) << 6) + lane;
        const float sgn = (waveId & vm) ? -RS2f : RS2f;
        #pragma unroll
        for (int j = 0; j < 8; ++j) {
            float4 q = p[(j << 8) + ps];
            vr[2*j]   = q.x * RS2f + vr[2*j]   * sgn;
            vi[2*j]   = q.y * RS2f + vi[2*j]   * sgn;
            vr[2*j+1] = q.z * RS2f + vr[2*j+1] * sgn;
            vi[2*j+1] = q.w * RS2f + vi[2*j+1] * sgn;
        }
    }
}

// ==================================================================
// 12-qubit circuit — EXACT R5/R8/R12 structure (77-78us measured,
// reads com directly; do not touch).
// ==================================================================
__global__ __launch_bounds__(256) void circuit_sa(const float* __restrict__ com,
                                                  const float* __restrict__ xf,
                                                  const float* __restrict__ qp,
                                                  float* __restrict__ out) {
    __shared__ float xbuf[8192];         // 32 KB exchange buffer
    __shared__ float ang[2048];          // 8 KB: com row, later xf row
    const int tid = threadIdx.x, lane = tid & 63, waveId = tid >> 6;
    const int b = blockIdx.x;
    if (tid < 128) ((float4*)ang)[tid] = ((const float4*)(com + b * 512))[tid];
    __syncthreads();
    float vr[16], vi[16];
    #pragma unroll
    for (int e = 0; e < 16; ++e) { vr[e] = 0.0f; vi[e] = 0.0f; }
    const float K9 = 0.044194173824159216f;   // 2^-4.5
    #pragma unroll
    for (int m = 0; m < 4; ++m) {
        int j = (lane << 3) | ((waveId & 1) << 2) | m;
        int rj = (int)(__brev((unsigned)j) >> 23);
        float s, c;
        sincosf(0.5f * ang[rj], &s, &c);
        vr[m << 2] = K9 * ((waveId & 2) ? s : c);
    }
    #pragma unroll 1
    for (int l = 0; l < 2; ++l) {
        { CMat M = mk_rot(qp, l, 0);  rot_wire<0 >(vr, vi, xbuf, waveId, lane, M); }
        { CMat M = mk_rot(qp, l, 1);  rot_wire<1 >(vr, vi, xbuf, waveId, lane, M); }
        { CMat M = mk_rot(qp, l, 2);  rot_wire<2 >(vr, vi, xbuf, waveId, lane, M); }
        { CMat M = mk_rot(qp, l, 3);  rot_wire<3 >(vr, vi, xbuf, waveId, lane, M); }
        { CMat M = mk_rot(qp, l, 4);  rot_wire<4 >(vr, vi, xbuf, waveId, lane, M); }
        { CMat M = mk_rot(qp, l, 5);  rot_wire<5 >(vr, vi, xbuf, waveId, lane, M); }
        { CMat M = mk_rot(qp, l, 6);  rot_wire<6 >(vr, vi, xbuf, waveId, lane, M); }
        { CMat M = mk_rot(qp, l, 7);  rot_wire<7 >(vr, vi, xbuf, waveId, lane, M); }
        { CMat M = mk_rot(qp, l, 8);  rot_wire<8 >(vr, vi, xbuf, waveId, lane, M); }
        { CMat M = mk_rot(qp, l, 9);  rot_wire<9 >(vr, vi, xbuf, waveId, lane, M); }
        { CMat M = mk_rot(qp, l, 10); rot_wire<10>(vr, vi, xbuf, waveId, lane, M); }
        { CMat M = mk_rot(qp, l, 11); rot_wire<11>(vr, vi, xbuf, waveId, lane, M); }
        if (l == 0) {                 // r = 1
            int j = lane;
            j ^= (j & 2)  ? 1  : 0;           // C(5,6)
            j ^= (j & 4)  ? 2  : 0;           // C(4,5)
            j ^= (j & 8)  ? 4  : 0;           // C(3,4)
            j ^= (j & 16) ? 8  : 0;           // C(2,3)
            j ^= (j & 32) ? 16 : 0;           // C(1,2)
            j ^= (waveId & 2) ? 32 : 0;       // C(0,1)
            shfl_perm(vr, vi, j);
            cnot<6,7>(vr,vi,xbuf,waveId,lane);   cnot<7,8>(vr,vi,xbuf,waveId,lane);
            cnot<8,9>(vr,vi,xbuf,waveId,lane);   cnot<9,10>(vr,vi,xbuf,waveId,lane);
            cnot<10,11>(vr,vi,xbuf,waveId,lane); cnot<11,0>(vr,vi,xbuf,waveId,lane);
        } else {                      // r = 2
            int j = lane;
            j ^= (j & 4)  ? 1  : 0;           // C(4,6)
            j ^= (j & 8)  ? 2  : 0;           // C(3,5)
            j ^= (j & 16) ? 4  : 0;           // C(2,4)
            j ^= (j & 32) ? 8  : 0;           // C(1,3)
            j ^= (waveId & 2) ? 16 : 0;       // C(0,2)
            shfl_perm(vr, vi, j);
            cnot<5,7>(vr,vi,xbuf,waveId,lane);   cnot<6,8>(vr,vi,xbuf,waveId,lane);
            cnot<7,9>(vr,vi,xbuf,waveId,lane);   cnot<8,10>(vr,vi,xbuf,waveId,lane);
            cnot<9,11>(vr,vi,xbuf,waveId,lane);  cnot<10,0>(vr,vi,xbuf,waveId,lane);
            cnot<11,1>(vr,vi,xbuf,waveId,lane);
        }
    }
    h_wire<1>(vr,vi,xbuf,waveId,lane);  h_wire<2>(vr,vi,xbuf,waveId,lane);
    h_wire<3>(vr,vi,xbuf,waveId,lane);  h_wire<4>(vr,vi,xbuf,waveId,lane);
    h_wire<5>(vr,vi,xbuf,waveId,lane);  h_wire<6>(vr,vi,xbuf,waveId,lane);
    h_wire<7>(vr,vi,xbuf,waveId,lane);  h_wire<8>(vr,vi,xbuf,waveId,lane);
    h_wire<9>(vr,vi,xbuf,waveId,lane);  h_wire<10>(vr,vi,xbuf,waveId,lane);
    h_wire<11>(vr,vi,xbuf,waveId,lane);
    {
        const float4* x4 = (const float4*)(xf + b * 2048);
        ((float4*)ang)[tid]       = x4[tid];
        ((float4*)ang)[tid + 256] = x4[tid + 256];
    }
    __syncthreads();
    exch_put(xbuf, (waveId << 6) + lane, vr, vi);
    {
        const float4* p = (const float4*)xbuf;
        const int ps = ((waveId ^ 2) << 6) + lane;
        const bool hi = waveId & 2;
        float acc = 0.0f;
        #pragma unroll
        for (int j = 0; j < 8; ++j) {
            float4 q = p[(j << 8) + ps];
            #pragma unroll
            for (int h = 0; h < 2; ++h) {
                const int e = 2*j + h;
                const float prr = h ? q.z : q.x;
                const float pii = h ? q.w : q.y;
                int v = (lane << 5) | ((waveId & 1) << 4) | e;
                int rv = (int)(__brev((unsigned)v) >> 21);
                float s, c;
                sincosf(0.5f * ang[rv], &s, &c);
                float nr = hi ? (s*prr + c*vr[e]) : (c*vr[e] - s*prr);
                float ni = hi ? (s*pii + c*vi[e]) : (c*vi[e] - s*pii);
                acc += nr*nr + ni*ni;
            }
        }
        if (!hi) acc = -acc;
        #pragma unroll
        for (int off = 32; off > 0; off >>= 1) acc += __shfl_down(acc, off, 64);
        __syncthreads();
        if (lane == 0) xbuf[waveId] = acc;
        __syncthreads();
        if (tid == 0) out[b] = xbuf[0] + xbuf[1] + xbuf[2] + xbuf[3];
    }
}

extern "C" void kernel_launch(void* const* d_in, const int* in_sizes, int n_in,
                              void* d_out, int out_size, void* d_ws, size_t ws_size,
                              hipStream_t stream) {
    const float* x    = (const float*)d_in[0];   // (1024,2048)
    const float* W    = (const float*)d_in[1];   // (512,2048)
    const float* bias = (const float*)d_in[2];   // (512,)
    const float* qp   = (const float*)d_in[3];   // (2,12,3)
    float* out = (float*)d_out;                  // (1024,)

    const size_t XC = (size_t)1024 * XSTR * 2;   // 8,519,680 B
    const size_t WC = (size_t)512 * XSTR * 2;    // 4,259,840 B
    const size_t SLAB = 2097152;                 // 2 MB per P slab
    const size_t BASE = XC + WC;
    if (ws_size >= BASE + SLAB) {
        unsigned short* xc = (unsigned short*)d_ws;
        unsigned short* wc = (unsigned short*)((char*)d_ws + XC);
        float* P = (float*)((char*)d_ws + BASE);
        int SK = 1;
        if      (ws_size >= BASE + 8 * SLAB) SK = 8;
        else if (ws_size >= BASE + 4 * SLAB) SK = 4;
        else if (ws_size >= BASE + 2 * SLAB) SK = 2;
        split_all<<<3072, 256, 0, stream>>>(x, W, xc, wc);
        dim3 g(16, 8, SK);                       // 64x64 tiles, split-K
        gemm64<<<g, 256, 0, stream>>>(xc, wc, P, 64 / SK);
        reduce_kernel<<<2048, 256, 0, stream>>>(P, bias, SK);
        circuit_sa<<<1024, 256, 0, stream>>>(P, x, qp, out);
    } else {
        float* P = (float*)d_ws;                 // 2 MB raw product
        dim3 g(16, 16);
        gemm_f32<<<g, 256, 0, stream>>>(x, W, P);
        reduce_kernel<<<2048, 256, 0, stream>>>(P, bias, 1);
        circuit_sa<<<1024, 256, 0, stream>>>(P, x, qp, out);
    }
}

// Round 16
// 149.058 us; speedup vs baseline: 1.0177x; 1.0177x over previous
//
#include <hip/hip_runtime.h>
#include <math.h>

#define RS2f 0.70710678118654752f

typedef __attribute__((ext_vector_type(8))) short bf16x8;
typedef __attribute__((ext_vector_type(4))) float f32x4;

__device__ __forceinline__ unsigned short f2bf(float f) {
    unsigned u = __float_as_uint(f);
    unsigned r = (u + 0x7fffu + ((u >> 16) & 1u)) >> 16;   // RNE
    return (unsigned short)r;
}
__device__ __forceinline__ float bf2f(unsigned short h) {
    return __uint_as_float(((unsigned)h) << 16);
}

// ==================================================================
// FUSED-CONVERT MFMA GEMM: reads fp32 A=x, B=W straight from d_in
// (cached), converts to bf16 hi/lo during LDS staging, accumulates
// hi*hi + lo*lo (split-bf16, same numerics as R7..R15).
// Rationale: every prior gemm that READ d_ws ran 4-5x slower than all
// issue models across 3 architectures; gemms reading d_in matched
// models exactly -> hypothesis: d_ws is not L2-cached. This kernel
// touches ws only for once-through P-slab writes.
// Tile 64x64, BK=64 fp32 (=128 bf16 as [hi 64 | lo 64]), 4 waves,
// padded LDS rows (136 shorts -> conflict-free writes), reg prefetch.
// Grid (16,8,SK).
// ==================================================================
__global__ __launch_bounds__(256) void gemm_fused(const float* __restrict__ A,  // 1024x2048
                                                  const float* __restrict__ B,  // 512x2048
                                                  float* __restrict__ P, int nch) {
    __shared__ short As[64 * 136];       // 17408 B
    __shared__ short Bs[64 * 136];       // 17408 B
    const int tid = threadIdx.x, lane = tid & 63, wv = tid >> 6;
    const int quad = lane >> 4, mrow = lane & 15;
    const int m0 = blockIdx.x * 64, n0 = blockIdx.y * 64;
    const int kb = blockIdx.z * nch * 64;          // fp32 K base
    const int srow = tid >> 2;           // 0..63
    const int sc = (tid & 3) * 16;       // fp32 col group 0,16,32,48

    f32x4 acc[4];
    #pragma unroll
    for (int j = 0; j < 4; ++j) acc[j] = (f32x4){0.f, 0.f, 0.f, 0.f};

    const float* Arow = A + (size_t)(m0 + srow) * 2048 + kb + sc;
    const float* Brow = B + (size_t)(n0 + srow) * 2048 + kb + sc;

    float4 av[4], bv[4];
    #pragma unroll
    for (int i = 0; i < 4; ++i) { av[i] = *(const float4*)(Arow + 4*i);
                                  bv[i] = *(const float4*)(Brow + 4*i); }

    for (int ch = 0; ch < nch; ++ch) {
        __syncthreads();
        #pragma unroll
        for (int i = 0; i < 4; ++i) {
            ushort4 hi, lo;
            hi.x = f2bf(av[i].x); lo.x = f2bf(av[i].x - bf2f(hi.x));
            hi.y = f2bf(av[i].y); lo.y = f2bf(av[i].y - bf2f(hi.y));
            hi.z = f2bf(av[i].z); lo.z = f2bf(av[i].z - bf2f(hi.z));
            hi.w = f2bf(av[i].w); lo.w = f2bf(av[i].w - bf2f(hi.w));
            *(ushort4*)&As[srow * 136 + sc + 4*i]      = hi;
            *(ushort4*)&As[srow * 136 + 64 + sc + 4*i] = lo;
            hi.x = f2bf(bv[i].x); lo.x = f2bf(bv[i].x - bf2f(hi.x));
            hi.y = f2bf(bv[i].y); lo.y = f2bf(bv[i].y - bf2f(hi.y));
            hi.z = f2bf(bv[i].z); lo.z = f2bf(bv[i].z - bf2f(hi.z));
            hi.w = f2bf(bv[i].w); lo.w = f2bf(bv[i].w - bf2f(hi.w));
            *(ushort4*)&Bs[srow * 136 + sc + 4*i]      = hi;
            *(ushort4*)&Bs[srow * 136 + 64 + sc + 4*i] = lo;
        }
        __syncthreads();
        if (ch + 1 < nch) {
            const int o = (ch + 1) * 64;
            #pragma unroll
            for (int i = 0; i < 4; ++i) { av[i] = *(const float4*)(Arow + o + 4*i);
                                          bv[i] = *(const float4*)(Brow + o + 4*i); }
        }
        #pragma unroll
        for (int s = 0; s < 4; ++s) {                // K-segments: 2 hi, 2 lo
            const int off = s * 32 + quad * 8;
            bf16x8 af = *(const bf16x8*)&As[(wv * 16 + mrow) * 136 + off];
            #pragma unroll
            for (int j = 0; j < 4; ++j) {
                bf16x8 bf = *(const bf16x8*)&Bs[(j * 16 + mrow) * 136 + off];
                acc[j] = __builtin_amdgcn_mfma_f32_16x16x32_bf16(af, bf, acc[j], 0, 0, 0);
            }
        }
    }
    // C/D layout: col = lane&15, row = quad*4 + r
    float* Pz = P + (size_t)blockIdx.z * 524288;
    #pragma unroll
    for (int j = 0; j < 4; ++j)
        #pragma unroll
        for (int r = 0; r < 4; ++r)
            Pz[(m0 + wv * 16 + quad * 4 + r) * 512 + n0 + j * 16 + mrow] = acc[j][r];
}

// ==================================================================
// reduce partials + bias -> slab 0
// ==================================================================
__global__ __launch_bounds__(256) void reduce_kernel(float* __restrict__ P,
                                                     const float* __restrict__ bias,
                                                     int SK) {
    int i = blockIdx.x * 256 + threadIdx.x;        // 512K total
    float s = bias[i & 511];
    for (int z = 0; z < SK; ++z) s += P[(size_t)z * 524288 + i];
    P[i] = s;
}

// ==================================================================
// Fallback fp32 GEMM (tiny ws): raw product to P; reduce adds bias.
// ==================================================================
__global__ __launch_bounds__(256) void gemm_f32(const float* __restrict__ A,
                                                const float* __restrict__ W,
                                                float* __restrict__ C) {
    __shared__ float Asf[64][33];
    __shared__ float Bsf[32][33];
    const int tid = threadIdx.x;
    const int m0 = blockIdx.x * 64;
    const int n0 = blockIdx.y * 32;
    const int tm = tid >> 4, tn = tid & 15;
    float acc[4][2] = {};
    for (int k0 = 0; k0 < 2048; k0 += 32) {
        #pragma unroll
        for (int i = 0; i < 8; ++i) {
            int idx = tid + i * 256;
            Asf[idx >> 5][idx & 31] = A[(m0 + (idx >> 5)) * 2048 + k0 + (idx & 31)];
        }
        #pragma unroll
        for (int i = 0; i < 4; ++i) {
            int idx = tid + i * 256;
            Bsf[idx >> 5][idx & 31] = W[(n0 + (idx >> 5)) * 2048 + k0 + (idx & 31)];
        }
        __syncthreads();
        #pragma unroll
        for (int kk = 0; kk < 32; ++kk) {
            float a0 = Asf[tm*4+0][kk], a1 = Asf[tm*4+1][kk];
            float a2 = Asf[tm*4+2][kk], a3 = Asf[tm*4+3][kk];
            float b0 = Bsf[tn*2+0][kk], b1 = Bsf[tn*2+1][kk];
            acc[0][0] += a0*b0; acc[0][1] += a0*b1;
            acc[1][0] += a1*b0; acc[1][1] += a1*b1;
            acc[2][0] += a2*b0; acc[2][1] += a2*b1;
            acc[3][0] += a3*b0; acc[3][1] += a3*b1;
        }
        __syncthreads();
    }
    #pragma unroll
    for (int r = 0; r < 4; ++r)
        #pragma unroll
        for (int c = 0; c < 2; ++c)
            C[(m0 + tm*4 + r) * 512 + n0 + tn*2 + c] = acc[r][c];
}

// ==================== circuit helpers (R5/R8/R12/R15 structure, 77-80us measured) ====================
struct CMat { float m00r,m00i,m01r,m01i,m10r,m10i,m11r,m11i; };

__device__ __forceinline__ CMat mk_rot(const float* __restrict__ qp, int l, int w) {
    const float* g = qp + (l * 12 + w) * 3;
    float phi = g[0], th = g[1], om = g[2];
    float st, ct, sa, ca, sb, cb;
    sincosf(0.5f * th, &st, &ct);
    sincosf(0.5f * (phi + om), &sa, &ca);
    sincosf(0.5f * (phi - om), &sb, &cb);
    CMat M;
    M.m00r =  ct * ca; M.m00i = -ct * sa;
    M.m01r = -st * cb; M.m01i = -st * sb;
    M.m10r =  st * cb; M.m10i = -st * sb;
    M.m11r =  ct * ca; M.m11i =  ct * sa;
    return M;
}

template<int W> struct WI {
    static constexpr int kind = (W == 0 || W == 7) ? 2 : ((W >= 1 && W <= 6) ? 1 : 0);
    static constexpr int eb   = (W >= 8) ? (11 - W) : 0;
    static constexpr int lm   = (W >= 1 && W <= 6) ? (1 << (6 - W)) : 0;
    static constexpr int vm   = (W == 0) ? 2 : ((W == 7) ? 1 : 0);
};

__device__ __forceinline__ void exch_put(float* xbuf, int slot,
                                         const float vr[16], const float vi[16]) {
    __syncthreads();
    float4* p = (float4*)xbuf;
    #pragma unroll
    for (int j = 0; j < 8; ++j)
        p[(j << 8) + slot] = make_float4(vr[2*j], vi[2*j], vr[2*j+1], vi[2*j+1]);
    __syncthreads();
}

__device__ __forceinline__ void shfl_perm(float vr[16], float vi[16], int src) {
    #pragma unroll
    for (int e = 0; e < 16; ++e) {
        vr[e] = __shfl(vr[e], src, 64);
        vi[e] = __shfl(vi[e], src, 64);
    }
}

template<int EB>
__device__ __forceinline__ void rot_local(float vr[16], float vi[16], const CMat& M) {
    #pragma unroll
    for (int e = 0; e < 16; ++e) if (!(e & (1 << EB))) {
        const int e1 = e | (1 << EB);
        float x0r = vr[e],  x0i = vi[e];
        float x1r = vr[e1], x1i = vi[e1];
        vr[e]  = M.m00r*x0r - M.m00i*x0i + M.m01r*x1r - M.m01i*x1i;
        vi[e]  = M.m00r*x0i + M.m00i*x0r + M.m01r*x1i + M.m01i*x1r;
        vr[e1] = M.m10r*x0r - M.m10i*x0i + M.m11r*x1r - M.m11i*x1i;
        vi[e1] = M.m10r*x0i + M.m10i*x0r + M.m11r*x1i + M.m11i*x1r;
    }
}

template<int LM>
__device__ __forceinline__ void rot_lane(float vr[16], float vi[16], int lane, const CMat& M) {
    const bool hi = lane & LM;
    const float Ar = hi ? M.m11r : M.m00r, Ai = hi ? M.m11i : M.m00i;
    const float Br = hi ? M.m10r : M.m01r, Bi = hi ? M.m10i : M.m01i;
    #pragma unroll
    for (int e = 0; e < 16; ++e) {
        float pr = __shfl_xor(vr[e], LM, 64);
        float pi = __shfl_xor(vi[e], LM, 64);
        float orr = vr[e], oi = vi[e];
        vr[e] = Ar*orr - Ai*oi + Br*pr - Bi*pi;
        vi[e] = Ar*oi + Ai*orr + Br*pi + Bi*pr;
    }
}

template<int VM>
__device__ __forceinline__ void rot_wave(float vr[16], float vi[16], float* xbuf,
                                         int waveId, int lane, const CMat& M) {
    exch_put(xbuf, (waveId << 6) + lane, vr, vi);
    const float4* p = (const float4*)xbuf;
    const int ps = ((waveId ^ VM) << 6) + lane;
    const bool hi = waveId & VM;
    const float Ar = hi ? M.m11r : M.m00r, Ai = hi ? M.m11i : M.m00i;
    const float Br = hi ? M.m10r : M.m01r, Bi = hi ? M.m10i : M.m01i;
    #pragma unroll
    for (int j = 0; j < 8; ++j) {
        float4 q = p[(j << 8) + ps];
        const int e0 = 2*j, e1 = 2*j + 1;
        float r0 = vr[e0], i0 = vi[e0], r1 = vr[e1], i1 = vi[e1];
        vr[e0] = Ar*r0 - Ai*i0 + Br*q.x - Bi*q.y;
        vi[e0] = Ar*i0 + Ai*r0 + Br*q.y + Bi*q.x;
        vr[e1] = Ar*r1 - Ai*i1 + Br*q.z - Bi*q.w;
        vi[e1] = Ar*i1 + Ai*r1 + Br*q.w + Bi*q.z;
    }
}

template<int W>
__device__ __forceinline__ void rot_wire(float vr[16], float vi[16], float* xbuf,
                                         int waveId, int lane, const CMat& M) {
    if constexpr (WI<W>::kind == 0)      rot_local<WI<W>::eb>(vr, vi, M);
    else if constexpr (WI<W>::kind == 1) rot_lane<WI<W>::lm>(vr, vi, lane, M);
    else                                 rot_wave<WI<W>::vm>(vr, vi, xbuf, waveId, lane, M);
}

template<int C, int T>
__device__ __forceinline__ void cnot(float vr[16], float vi[16], float* xbuf,
                                     int waveId, int lane) {
    constexpr int ck = WI<C>::kind, tk = WI<T>::kind;
    if constexpr (ck == 0 && tk == 0) {
        constexpr int cb = 1 << WI<C>::eb, tb = 1 << WI<T>::eb;
        #pragma unroll
        for (int e = 0; e < 16; ++e) if ((e & cb) && !(e & tb)) {
            const int e1 = e | tb;
            float t = vr[e]; vr[e] = vr[e1]; vr[e1] = t;
            t = vi[e]; vi[e] = vi[e1]; vi[e1] = t;
        }
    } else if constexpr (ck == 0 && tk == 1) {
        constexpr int cb = 1 << WI<C>::eb, tm = WI<T>::lm;
        #pragma unroll
        for (int e = 0; e < 16; ++e) if (e & cb) {
            vr[e] = __shfl_xor(vr[e], tm, 64);
            vi[e] = __shfl_xor(vi[e], tm, 64);
        }
    } else if constexpr (ck == 0 && tk == 2) {
        constexpr int cb = 1 << WI<C>::eb, vm = WI<T>::vm;
        exch_put(xbuf, (waveId << 6) + lane, vr, vi);
        const float4* p = (const float4*)xbuf;
        const int ps = ((waveId ^ vm) << 6) + lane;
        #pragma unroll
        for (int j = 0; j < 8; ++j) {
            if ((((2*j) & cb) != 0) || (((2*j+1) & cb) != 0)) {
                float4 q = p[(j << 8) + ps];
                if (((2*j) & cb) != 0)   { vr[2*j]   = q.x; vi[2*j]   = q.y; }
                if (((2*j+1) & cb) != 0) { vr[2*j+1] = q.z; vi[2*j+1] = q.w; }
            }
        }
    } else if constexpr (ck == 1 && tk == 0) {
        constexpr int cm = WI<C>::lm, tb = 1 << WI<T>::eb;
        const bool cc = lane & cm;
        #pragma unroll
        for (int e = 0; e < 16; ++e) if (!(e & tb)) {
            const int e1 = e | tb;
            float a = vr[e], bb = vr[e1];
            vr[e] = cc ? bb : a; vr[e1] = cc ? a : bb;
            a = vi[e]; bb = vi[e1];
            vi[e] = cc ? bb : a; vi[e1] = cc ? a : bb;
        }
    } else if constexpr (ck == 1 && tk == 1) {
        constexpr int cm = WI<C>::lm, tm = WI<T>::lm;
        const int src = (lane & cm) ? (lane ^ tm) : lane;
        shfl_perm(vr, vi, src);
    } else if constexpr (ck == 1 && tk == 2) {
        constexpr int cm = WI<C>::lm, vm = WI<T>::vm;
        exch_put(xbuf, (waveId << 6) + lane, vr, vi);
        const float4* p = (const float4*)xbuf;
        const int ps = ((waveId ^ vm) << 6) + lane;
        const bool take = lane & cm;
        #pragma unroll
        for (int j = 0; j < 8; ++j) {
            float4 q = p[(j << 8) + ps];
            vr[2*j]   = take ? q.x : vr[2*j];   vi[2*j]   = take ? q.y : vi[2*j];
            vr[2*j+1] = take ? q.z : vr[2*j+1]; vi[2*j+1] = take ? q.w : vi[2*j+1];
        }
    } else if constexpr (ck == 2 && tk == 0) {
        constexpr int vm = WI<C>::vm, tb = 1 << WI<T>::eb;
        if (waveId & vm) {
            #pragma unroll
            for (int e = 0; e < 16; ++e) if (!(e & tb)) {
                const int e1 = e | tb;
                float t = vr[e]; vr[e] = vr[e1]; vr[e1] = t;
                t = vi[e]; vi[e] = vi[e1]; vi[e1] = t;
            }
        }
    } else {
        constexpr int vm = WI<C>::vm, tm = WI<T>::lm;
        if (waveId & vm) {
            #pragma unroll
            for (int e = 0; e < 16; ++e) {
                vr[e] = __shfl_xor(vr[e], tm, 64);
                vi[e] = __shfl_xor(vi[e], tm, 64);
            }
        }
    }
}

template<int W>
__device__ __forceinline__ void h_wire(float vr[16], float vi[16], float* xbuf,
                                       int waveId, int lane) {
    if constexpr (WI<W>::kind == 0) {
        constexpr int tb = 1 << WI<W>::eb;
        #pragma unroll
        for (int e = 0; e < 16; ++e) if (!(e & tb)) {
            const int e1 = e | tb;
            float x0 = vr[e], x1 = vr[e1];
            vr[e] = (x0 + x1) * RS2f; vr[e1] = (x0 - x1) * RS2f;
            x0 = vi[e]; x1 = vi[e1];
            vi[e] = (x0 + x1) * RS2f; vi[e1] = (x0 - x1) * RS2f;
        }
    } else if constexpr (WI<W>::kind == 1) {
        constexpr int m = WI<W>::lm;
        const float sgn = (lane & m) ? -RS2f : RS2f;
        #pragma unroll
        for (int e = 0; e < 16; ++e) {
            float pr = __shfl_xor(vr[e], m, 64);
            float pi = __shfl_xor(vi[e], m, 64);
            vr[e] = pr * RS2f + vr[e] * sgn;
            vi[e] = pi * RS2f + vi[e] * sgn;
        }
    } else {
        constexpr int vm = WI<W>::vm;
        exch_put(xbuf, (waveId << 6) + lane, vr, vi);
        const float4* p = (const float4*)xbuf;
        const int ps = ((waveId ^ vm) << 6) + lane;
        const float sgn = (waveId & vm) ? -RS2f : RS2f;
        #pragma unroll
        for (int j = 0; j < 8; ++j) {
            float4 q = p[(j << 8) + ps];
            vr[2*j]   = q.x * RS2f + vr[2*j]   * sgn;
            vi[2*j]   = q.y * RS2f + vi[2*j]   * sgn;
            vr[2*j+1] = q.z * RS2f + vr[2*j+1] * sgn;
            vi[2*j+1] = q.w * RS2f + vi[2*j+1] * sgn;
        }
    }
}

// ==================================================================
// 12-qubit circuit — EXACT R5/R8/R12/R15 structure (77-80us, do not touch).
// ==================================================================
__global__ __launch_bounds__(256) void circuit_sa(const float* __restrict__ com,
                                                  const float* __restrict__ xf,
                                                  const float* __restrict__ qp,
                                                  float* __restrict__ out) {
    __shared__ float xbuf[8192];         // 32 KB exchange buffer
    __shared__ float ang[2048];          // 8 KB: com row, later xf row
    const int tid = threadIdx.x, lane = tid & 63, waveId = tid >> 6;
    const int b = blockIdx.x;
    if (tid < 128) ((float4*)ang)[tid] = ((const float4*)(com + b * 512))[tid];
    __syncthreads();
    float vr[16], vi[16];
    #pragma unroll
    for (int e = 0; e < 16; ++e) { vr[e] = 0.0f; vi[e] = 0.0f; }
    const float K9 = 0.044194173824159216f;   // 2^-4.5
    #pragma unroll
    for (int m = 0; m < 4; ++m) {
        int j = (lane << 3) | ((waveId & 1) << 2) | m;
        int rj = (int)(__brev((unsigned)j) >> 23);
        float s, c;
        sincosf(0.5f * ang[rj], &s, &c);
        vr[m << 2] = K9 * ((waveId & 2) ? s : c);
    }
    #pragma unroll 1
    for (int l = 0; l < 2; ++l) {
        { CMat M = mk_rot(qp, l, 0);  rot_wire<0 >(vr, vi, xbuf, waveId, lane, M); }
        { CMat M = mk_rot(qp, l, 1);  rot_wire<1 >(vr, vi, xbuf, waveId, lane, M); }
        { CMat M = mk_rot(qp, l, 2);  rot_wire<2 >(vr, vi, xbuf, waveId, lane, M); }
        { CMat M = mk_rot(qp, l, 3);  rot_wire<3 >(vr, vi, xbuf, waveId, lane, M); }
        { CMat M = mk_rot(qp, l, 4);  rot_wire<4 >(vr, vi, xbuf, waveId, lane, M); }
        { CMat M = mk_rot(qp, l, 5);  rot_wire<5 >(vr, vi, xbuf, waveId, lane, M); }
        { CMat M = mk_rot(qp, l, 6);  rot_wire<6 >(vr, vi, xbuf, waveId, lane, M); }
        { CMat M = mk_rot(qp, l, 7);  rot_wire<7 >(vr, vi, xbuf, waveId, lane, M); }
        { CMat M = mk_rot(qp, l, 8);  rot_wire<8 >(vr, vi, xbuf, waveId, lane, M); }
        { CMat M = mk_rot(qp, l, 9);  rot_wire<9 >(vr, vi, xbuf, waveId, lane, M); }
        { CMat M = mk_rot(qp, l, 10); rot_wire<10>(vr, vi, xbuf, waveId, lane, M); }
        { CMat M = mk_rot(qp, l, 11); rot_wire<11>(vr, vi, xbuf, waveId, lane, M); }
        if (l == 0) {                 // r = 1
            int j = lane;
            j ^= (j & 2)  ? 1  : 0;           // C(5,6)
            j ^= (j & 4)  ? 2  : 0;           // C(4,5)
            j ^= (j & 8)  ? 4  : 0;           // C(3,4)
            j ^= (j & 16) ? 8  : 0;           // C(2,3)
            j ^= (j & 32) ? 16 : 0;           // C(1,2)
            j ^= (waveId & 2) ? 32 : 0;       // C(0,1)
            shfl_perm(vr, vi, j);
            cnot<6,7>(vr,vi,xbuf,waveId,lane);   cnot<7,8>(vr,vi,xbuf,waveId,lane);
            cnot<8,9>(vr,vi,xbuf,waveId,lane);   cnot<9,10>(vr,vi,xbuf,waveId,lane);
            cnot<10,11>(vr,vi,xbuf,waveId,lane); cnot<11,0>(vr,vi,xbuf,waveId,lane);
        } else {                      // r = 2
            int j = lane;
            j ^= (j & 4)  ? 1  : 0;           // C(4,6)
            j ^= (j & 8)  ? 2  : 0;           // C(3,5)
            j ^= (j & 16) ? 4  : 0;           // C(2,4)
            j ^= (j & 32) ? 8  : 0;           // C(1,3)
            j ^= (waveId & 2) ? 16 : 0;       // C(0,2)
            shfl_perm(vr, vi, j);
            cnot<5,7>(vr,vi,xbuf,waveId,lane);   cnot<6,8>(vr,vi,xbuf,waveId,lane);
            cnot<7,9>(vr,vi,xbuf,waveId,lane);   cnot<8,10>(vr,vi,xbuf,waveId,lane);
            cnot<9,11>(vr,vi,xbuf,waveId,lane);  cnot<10,0>(vr,vi,xbuf,waveId,lane);
            cnot<11,1>(vr,vi,xbuf,waveId,lane);
        }
    }
    h_wire<1>(vr,vi,xbuf,waveId,lane);  h_wire<2>(vr,vi,xbuf,waveId,lane);
    h_wire<3>(vr,vi,xbuf,waveId,lane);  h_wire<4>(vr,vi,xbuf,waveId,lane);
    h_wire<5>(vr,vi,xbuf,waveId,lane);  h_wire<6>(vr,vi,xbuf,waveId,lane);
    h_wire<7>(vr,vi,xbuf,waveId,lane);  h_wire<8>(vr,vi,xbuf,waveId,lane);
    h_wire<9>(vr,vi,xbuf,waveId,lane);  h_wire<10>(vr,vi,xbuf,waveId,lane);
    h_wire<11>(vr,vi,xbuf,waveId,lane);
    {
        const float4* x4 = (const float4*)(xf + b * 2048);
        ((float4*)ang)[tid]       = x4[tid];
        ((float4*)ang)[tid + 256] = x4[tid + 256];
    }
    __syncthreads();
    exch_put(xbuf, (waveId << 6) + lane, vr, vi);
    {
        const float4* p = (const float4*)xbuf;
        const int ps = ((waveId ^ 2) << 6) + lane;
        const bool hi = waveId & 2;
        float acc = 0.0f;
        #pragma unroll
        for (int j = 0; j < 8; ++j) {
            float4 q = p[(j << 8) + ps];
            #pragma unroll
            for (int h = 0; h < 2; ++h) {
                const int e = 2*j + h;
                const float prr = h ? q.z : q.x;
                const float pii = h ? q.w : q.y;
                int v = (lane << 5) | ((waveId & 1) << 4) | e;
                int rv = (int)(__brev((unsigned)v) >> 21);
                float s, c;
                sincosf(0.5f * ang[rv], &s, &c);
                float nr = hi ? (s*prr + c*vr[e]) : (c*vr[e] - s*prr);
                float ni = hi ? (s*pii + c*vi[e]) : (c*vi[e] - s*pii);
                acc += nr*nr + ni*ni;
            }
        }
        if (!hi) acc = -acc;
        #pragma unroll
        for (int off = 32; off > 0; off >>= 1) acc += __shfl_down(acc, off, 64);
        __syncthreads();
        if (lane == 0) xbuf[waveId] = acc;
        __syncthreads();
        if (tid == 0) out[b] = xbuf[0] + xbuf[1] + xbuf[2] + xbuf[3];
    }
}

extern "C" void kernel_launch(void* const* d_in, const int* in_sizes, int n_in,
                              void* d_out, int out_size, void* d_ws, size_t ws_size,
                              hipStream_t stream) {
    const float* x    = (const float*)d_in[0];   // (1024,2048)
    const float* W    = (const float*)d_in[1];   // (512,2048)
    const float* bias = (const float*)d_in[2];   // (512,)
    const float* qp   = (const float*)d_in[3];   // (2,12,3)
    float* out = (float*)d_out;                  // (1024,)

    const size_t SLAB = 2097152;                 // 2 MB per P slab
    float* P = (float*)d_ws;
    if (ws_size >= 2 * SLAB) {
        int SK = (ws_size >= 4 * SLAB) ? 4 : 2;
        dim3 g(16, 8, SK);                       // 64x64 tiles, split-K
        gemm_fused<<<g, 256, 0, stream>>>(x, W, P, 32 / SK);   // nch = 2048/64/SK
        reduce_kernel<<<2048, 256, 0, stream>>>(P, bias, SK);
        circuit_sa<<<1024, 256, 0, stream>>>(P, x, qp, out);
    } else {
        dim3 g(16, 16);
        gemm_f32<<<g, 256, 0, stream>>>(x, W, P);
        reduce_kernel<<<2048, 256, 0, stream>>>(P, bias, 1);
        circuit_sa<<<1024, 256, 0, stream>>>(P, x, qp, out);
    }
}

// Round 17
// 148.611 us; speedup vs baseline: 1.0207x; 1.0030x over previous
//
#include <hip/hip_runtime.h>
#include <hip/hip_bf16.h>
#include <math.h>

#define RS2f 0.70710678118654752f

typedef __attribute__((ext_vector_type(8))) short bf16x8;
typedef __attribute__((ext_vector_type(4))) float f32x4;

__device__ __forceinline__ float bf2f(unsigned short h) {
    return __uint_as_float(((unsigned)h) << 16);
}
// HW packed fp32x2 -> bf16x2 (v_cvt_pk_bf16_f32 on gfx950, RNE)
__device__ __forceinline__ ushort2 pk2(float a, float b) {
    union { __hip_bfloat162 h; ushort2 s; } u;
    u.h = __float22bfloat162_rn(make_float2(a, b));
    return u.s;
}

// ==================================================================
// FUSED-CONVERT MFMA GEMM (R16 structure). Changes vs R16:
//  1) conversion uses HW packed cvt (1 inst / 2 values vs ~14) --
//     R16 post-mortem: ~400 conversion VALU/thread/chunk was the
//     gemm's dominant cost.
//  2) SK=8 -> 1024 blocks = 4 blocks/CU (double TLP for the
//     VALU-bound conversion phase).
// Tile 64x64, BK=64 fp32 (=128 bf16 [hi|lo]), 4 waves, padded LDS.
// ==================================================================
__global__ __launch_bounds__(256) void gemm_fused(const float* __restrict__ A,  // 1024x2048
                                                  const float* __restrict__ B,  // 512x2048
                                                  float* __restrict__ P, int nch) {
    __shared__ short As[64 * 136];       // 17408 B
    __shared__ short Bs[64 * 136];       // 17408 B
    const int tid = threadIdx.x, lane = tid & 63, wv = tid >> 6;
    const int quad = lane >> 4, mrow = lane & 15;
    const int m0 = blockIdx.x * 64, n0 = blockIdx.y * 64;
    const int kb = blockIdx.z * nch * 64;          // fp32 K base
    const int srow = tid >> 2;           // 0..63
    const int sc = (tid & 3) * 16;       // fp32 col group 0,16,32,48

    f32x4 acc[4];
    #pragma unroll
    for (int j = 0; j < 4; ++j) acc[j] = (f32x4){0.f, 0.f, 0.f, 0.f};

    const float* Arow = A + (size_t)(m0 + srow) * 2048 + kb + sc;
    const float* Brow = B + (size_t)(n0 + srow) * 2048 + kb + sc;

    float4 av[4], bv[4];
    #pragma unroll
    for (int i = 0; i < 4; ++i) { av[i] = *(const float4*)(Arow + 4*i);
                                  bv[i] = *(const float4*)(Brow + 4*i); }

    for (int ch = 0; ch < nch; ++ch) {
        __syncthreads();
        #pragma unroll
        for (int i = 0; i < 4; ++i) {
            ushort2 h0 = pk2(av[i].x, av[i].y);
            ushort2 h1 = pk2(av[i].z, av[i].w);
            ushort2 l0 = pk2(av[i].x - bf2f(h0.x), av[i].y - bf2f(h0.y));
            ushort2 l1 = pk2(av[i].z - bf2f(h1.x), av[i].w - bf2f(h1.y));
            *(ushort4*)&As[srow * 136 + sc + 4*i]      = make_ushort4(h0.x, h0.y, h1.x, h1.y);
            *(ushort4*)&As[srow * 136 + 64 + sc + 4*i] = make_ushort4(l0.x, l0.y, l1.x, l1.y);
            h0 = pk2(bv[i].x, bv[i].y);
            h1 = pk2(bv[i].z, bv[i].w);
            l0 = pk2(bv[i].x - bf2f(h0.x), bv[i].y - bf2f(h0.y));
            l1 = pk2(bv[i].z - bf2f(h1.x), bv[i].w - bf2f(h1.y));
            *(ushort4*)&Bs[srow * 136 + sc + 4*i]      = make_ushort4(h0.x, h0.y, h1.x, h1.y);
            *(ushort4*)&Bs[srow * 136 + 64 + sc + 4*i] = make_ushort4(l0.x, l0.y, l1.x, l1.y);
        }
        __syncthreads();
        if (ch + 1 < nch) {
            const int o = (ch + 1) * 64;
            #pragma unroll
            for (int i = 0; i < 4; ++i) { av[i] = *(const float4*)(Arow + o + 4*i);
                                          bv[i] = *(const float4*)(Brow + o + 4*i); }
        }
        #pragma unroll
        for (int s = 0; s < 4; ++s) {                // K-segments: 2 hi, 2 lo
            const int off = s * 32 + quad * 8;
            bf16x8 af = *(const bf16x8*)&As[(wv * 16 + mrow) * 136 + off];
            #pragma unroll
            for (int j = 0; j < 4; ++j) {
                bf16x8 bf = *(const bf16x8*)&Bs[(j * 16 + mrow) * 136 + off];
                acc[j] = __builtin_amdgcn_mfma_f32_16x16x32_bf16(af, bf, acc[j], 0, 0, 0);
            }
        }
    }
    // C/D layout: col = lane&15, row = quad*4 + r
    float* Pz = P + (size_t)blockIdx.z * 524288;
    #pragma unroll
    for (int j = 0; j < 4; ++j)
        #pragma unroll
        for (int r = 0; r < 4; ++r)
            Pz[(m0 + wv * 16 + quad * 4 + r) * 512 + n0 + j * 16 + mrow] = acc[j][r];
}

// ==================================================================
// reduce partials + bias -> slab 0
// ==================================================================
__global__ __launch_bounds__(256) void reduce_kernel(float* __restrict__ P,
                                                     const float* __restrict__ bias,
                                                     int SK) {
    int i = blockIdx.x * 256 + threadIdx.x;        // 512K total
    float s = bias[i & 511];
    for (int z = 0; z < SK; ++z) s += P[(size_t)z * 524288 + i];
    P[i] = s;
}

// ==================================================================
// Fallback fp32 GEMM (tiny ws): raw product to P; reduce adds bias.
// ==================================================================
__global__ __launch_bounds__(256) void gemm_f32(const float* __restrict__ A,
                                                const float* __restrict__ W,
                                                float* __restrict__ C) {
    __shared__ float Asf[64][33];
    __shared__ float Bsf[32][33];
    const int tid = threadIdx.x;
    const int m0 = blockIdx.x * 64;
    const int n0 = blockIdx.y * 32;
    const int tm = tid >> 4, tn = tid & 15;
    float acc[4][2] = {};
    for (int k0 = 0; k0 < 2048; k0 += 32) {
        #pragma unroll
        for (int i = 0; i < 8; ++i) {
            int idx = tid + i * 256;
            Asf[idx >> 5][idx & 31] = A[(m0 + (idx >> 5)) * 2048 + k0 + (idx & 31)];
        }
        #pragma unroll
        for (int i = 0; i < 4; ++i) {
            int idx = tid + i * 256;
            Bsf[idx >> 5][idx & 31] = W[(n0 + (idx >> 5)) * 2048 + k0 + (idx & 31)];
        }
        __syncthreads();
        #pragma unroll
        for (int kk = 0; kk < 32; ++kk) {
            float a0 = Asf[tm*4+0][kk], a1 = Asf[tm*4+1][kk];
            float a2 = Asf[tm*4+2][kk], a3 = Asf[tm*4+3][kk];
            float b0 = Bsf[tn*2+0][kk], b1 = Bsf[tn*2+1][kk];
            acc[0][0] += a0*b0; acc[0][1] += a0*b1;
            acc[1][0] += a1*b0; acc[1][1] += a1*b1;
            acc[2][0] += a2*b0; acc[2][1] += a2*b1;
            acc[3][0] += a3*b0; acc[3][1] += a3*b1;
        }
        __syncthreads();
    }
    #pragma unroll
    for (int r = 0; r < 4; ++r)
        #pragma unroll
        for (int c = 0; c < 2; ++c)
            C[(m0 + tm*4 + r) * 512 + n0 + tn*2 + c] = acc[r][c];
}

// ==================== circuit helpers (R5/R8/R12/R15 structure, 77-80us measured) ====================
struct CMat { float m00r,m00i,m01r,m01i,m10r,m10i,m11r,m11i; };

__device__ __forceinline__ CMat mk_rot(const float* __restrict__ qp, int l, int w) {
    const float* g = qp + (l * 12 + w) * 3;
    float phi = g[0], th = g[1], om = g[2];
    float st, ct, sa, ca, sb, cb;
    sincosf(0.5f * th, &st, &ct);
    sincosf(0.5f * (phi + om), &sa, &ca);
    sincosf(0.5f * (phi - om), &sb, &cb);
    CMat M;
    M.m00r =  ct * ca; M.m00i = -ct * sa;
    M.m01r = -st * cb; M.m01i = -st * sb;
    M.m10r =  st * cb; M.m10i = -st * sb;
    M.m11r =  ct * ca; M.m11i =  ct * sa;
    return M;
}

template<int W> struct WI {
    static constexpr int kind = (W == 0 || W == 7) ? 2 : ((W >= 1 && W <= 6) ? 1 : 0);
    static constexpr int eb   = (W >= 8) ? (11 - W) : 0;
    static constexpr int lm   = (W >= 1 && W <= 6) ? (1 << (6 - W)) : 0;
    static constexpr int vm   = (W == 0) ? 2 : ((W == 7) ? 1 : 0);
};

__device__ __forceinline__ void exch_put(float* xbuf, int slot,
                                         const float vr[16], const float vi[16]) {
    __syncthreads();
    float4* p = (float4*)xbuf;
    #pragma unroll
    for (int j = 0; j < 8; ++j)
        p[(j << 8) + slot] = make_float4(vr[2*j], vi[2*j], vr[2*j+1], vi[2*j+1]);
    __syncthreads();
}

__device__ __forceinline__ void shfl_perm(float vr[16], float vi[16], int src) {
    #pragma unroll
    for (int e = 0; e < 16; ++e) {
        vr[e] = __shfl(vr[e], src, 64);
        vi[e] = __shfl(vi[e], src, 64);
    }
}

template<int EB>
__device__ __forceinline__ void rot_local(float vr[16], float vi[16], const CMat& M) {
    #pragma unroll
    for (int e = 0; e < 16; ++e) if (!(e & (1 << EB))) {
        const int e1 = e | (1 << EB);
        float x0r = vr[e],  x0i = vi[e];
        float x1r = vr[e1], x1i = vi[e1];
        vr[e]  = M.m00r*x0r - M.m00i*x0i + M.m01r*x1r - M.m01i*x1i;
        vi[e]  = M.m00r*x0i + M.m00i*x0r + M.m01r*x1i + M.m01i*x1r;
        vr[e1] = M.m10r*x0r - M.m10i*x0i + M.m11r*x1r - M.m11i*x1i;
        vi[e1] = M.m10r*x0i + M.m10i*x0r + M.m11r*x1i + M.m11i*x1r;
    }
}

template<int LM>
__device__ __forceinline__ void rot_lane(float vr[16], float vi[16], int lane, const CMat& M) {
    const bool hi = lane & LM;
    const float Ar = hi ? M.m11r : M.m00r, Ai = hi ? M.m11i : M.m00i;
    const float Br = hi ? M.m10r : M.m01r, Bi = hi ? M.m10i : M.m01i;
    #pragma unroll
    for (int e = 0; e < 16; ++e) {
        float pr = __shfl_xor(vr[e], LM, 64);
        float pi = __shfl_xor(vi[e], LM, 64);
        float orr = vr[e], oi = vi[e];
        vr[e] = Ar*orr - Ai*oi + Br*pr - Bi*pi;
        vi[e] = Ar*oi + Ai*orr + Br*pi + Bi*pr;
    }
}

template<int VM>
__device__ __forceinline__ void rot_wave(float vr[16], float vi[16], float* xbuf,
                                         int waveId, int lane, const CMat& M) {
    exch_put(xbuf, (waveId << 6) + lane, vr, vi);
    const float4* p = (const float4*)xbuf;
    const int ps = ((waveId ^ VM) << 6) + lane;
    const bool hi = waveId & VM;
    const float Ar = hi ? M.m11r : M.m00r, Ai = hi ? M.m11i : M.m00i;
    const float Br = hi ? M.m10r : M.m01r, Bi = hi ? M.m10i : M.m01i;
    #pragma unroll
    for (int j = 0; j < 8; ++j) {
        float4 q = p[(j << 8) + ps];
        const int e0 = 2*j, e1 = 2*j + 1;
        float r0 = vr[e0], i0 = vi[e0], r1 = vr[e1], i1 = vi[e1];
        vr[e0] = Ar*r0 - Ai*i0 + Br*q.x - Bi*q.y;
        vi[e0] = Ar*i0 + Ai*r0 + Br*q.y + Bi*q.x;
        vr[e1] = Ar*r1 - Ai*i1 + Br*q.z - Bi*q.w;
        vi[e1] = Ar*i1 + Ai*r1 + Br*q.w + Bi*q.z;
    }
}

template<int W>
__device__ __forceinline__ void rot_wire(float vr[16], float vi[16], float* xbuf,
                                         int waveId, int lane, const CMat& M) {
    if constexpr (WI<W>::kind == 0)      rot_local<WI<W>::eb>(vr, vi, M);
    else if constexpr (WI<W>::kind == 1) rot_lane<WI<W>::lm>(vr, vi, lane, M);
    else                                 rot_wave<WI<W>::vm>(vr, vi, xbuf, waveId, lane, M);
}

template<int C, int T>
__device__ __forceinline__ void cnot(float vr[16], float vi[16], float* xbuf,
                                     int waveId, int lane) {
    constexpr int ck = WI<C>::kind, tk = WI<T>::kind;
    if constexpr (ck == 0 && tk == 0) {
        constexpr int cb = 1 << WI<C>::eb, tb = 1 << WI<T>::eb;
        #pragma unroll
        for (int e = 0; e < 16; ++e) if ((e & cb) && !(e & tb)) {
            const int e1 = e | tb;
            float t = vr[e]; vr[e] = vr[e1]; vr[e1] = t;
            t = vi[e]; vi[e] = vi[e1]; vi[e1] = t;
        }
    } else if constexpr (ck == 0 && tk == 1) {
        constexpr int cb = 1 << WI<C>::eb, tm = WI<T>::lm;
        #pragma unroll
        for (int e = 0; e < 16; ++e) if (e & cb) {
            vr[e] = __shfl_xor(vr[e], tm, 64);
            vi[e] = __shfl_xor(vi[e], tm, 64);
        }
    } else if constexpr (ck == 0 && tk == 2) {
        constexpr int cb = 1 << WI<C>::eb, vm = WI<T>::vm;
        exch_put(xbuf, (waveId << 6) + lane, vr, vi);
        const float4* p = (const float4*)xbuf;
        const int ps = ((waveId ^ vm) << 6) + lane;
        #pragma unroll
        for (int j = 0; j < 8; ++j) {
            if ((((2*j) & cb) != 0) || (((2*j+1) & cb) != 0)) {
                float4 q = p[(j << 8) + ps];
                if (((2*j) & cb) != 0)   { vr[2*j]   = q.x; vi[2*j]   = q.y; }
                if (((2*j+1) & cb) != 0) { vr[2*j+1] = q.z; vi[2*j+1] = q.w; }
            }
        }
    } else if constexpr (ck == 1 && tk == 0) {
        constexpr int cm = WI<C>::lm, tb = 1 << WI<T>::eb;
        const bool cc = lane & cm;
        #pragma unroll
        for (int e = 0; e < 16; ++e) if (!(e & tb)) {
            const int e1 = e | tb;
            float a = vr[e], bb = vr[e1];
            vr[e] = cc ? bb : a; vr[e1] = cc ? a : bb;
            a = vi[e]; bb = vi[e1];
            vi[e] = cc ? bb : a; vi[e1] = cc ? a : bb;
        }
    } else if constexpr (ck == 1 && tk == 1) {
        constexpr int cm = WI<C>::lm, tm = WI<T>::lm;
        const int src = (lane & cm) ? (lane ^ tm) : lane;
        shfl_perm(vr, vi, src);
    } else if constexpr (ck == 1 && tk == 2) {
        constexpr int cm = WI<C>::lm, vm = WI<T>::vm;
        exch_put(xbuf, (waveId << 6) + lane, vr, vi);
        const float4* p = (const float4*)xbuf;
        const int ps = ((waveId ^ vm) << 6) + lane;
        const bool take = lane & cm;
        #pragma unroll
        for (int j = 0; j < 8; ++j) {
            float4 q = p[(j << 8) + ps];
            vr[2*j]   = take ? q.x : vr[2*j];   vi[2*j]   = take ? q.y : vi[2*j];
            vr[2*j+1] = take ? q.z : vr[2*j+1]; vi[2*j+1] = take ? q.w : vi[2*j+1];
        }
    } else if constexpr (ck == 2 && tk == 0) {
        constexpr int vm = WI<C>::vm, tb = 1 << WI<T>::eb;
        if (waveId & vm) {
            #pragma unroll
            for (int e = 0; e < 16; ++e) if (!(e & tb)) {
                const int e1 = e | tb;
                float t = vr[e]; vr[e] = vr[e1]; vr[e1] = t;
                t = vi[e]; vi[e] = vi[e1]; vi[e1] = t;
            }
        }
    } else {
        constexpr int vm = WI<C>::vm, tm = WI<T>::lm;
        if (waveId & vm) {
            #pragma unroll
            for (int e = 0; e < 16; ++e) {
                vr[e] = __shfl_xor(vr[e], tm, 64);
                vi[e] = __shfl_xor(vi[e], tm, 64);
            }
        }
    }
}

template<int W>
__device__ __forceinline__ void h_wire(float vr[16], float vi[16], float* xbuf,
                                       int waveId, int lane) {
    if constexpr (WI<W>::kind == 0) {
        constexpr int tb = 1 << WI<W>::eb;
        #pragma unroll
        for (int e = 0; e < 16; ++e) if (!(e & tb)) {
            const int e1 = e | tb;
            float x0 = vr[e], x1 = vr[e1];
            vr[e] = (x0 + x1) * RS2f; vr[e1] = (x0 - x1) * RS2f;
            x0 = vi[e]; x1 = vi[e1];
            vi[e] = (x0 + x1) * RS2f; vi[e1] = (x0 - x1) * RS2f;
        }
    } else if constexpr (WI<W>::kind == 1) {
        constexpr int m = WI<W>::lm;
        const float sgn = (lane & m) ? -RS2f : RS2f;
        #pragma unroll
        for (int e = 0; e < 16; ++e) {
            float pr = __shfl_xor(vr[e], m, 64);
            float pi = __shfl_xor(vi[e], m, 64);
            vr[e] = pr * RS2f + vr[e] * sgn;
            vi[e] = pi * RS2f + vi[e] * sgn;
        }
    } else {
        constexpr int vm = WI<W>::vm;
        exch_put(xbuf, (waveId << 6) + lane, vr, vi);
        const float4* p = (const float4*)xbuf;
        const int ps = ((waveId ^ vm) << 6) + lane;
        const float sgn = (waveId & vm) ? -RS2f : RS2f;
        #pragma unroll
        for (int j = 0; j < 8; ++j) {
            float4 q = p[(j << 8) + ps];
            vr[2*j]   = q.x * RS2f + vr[2*j]   * sgn;
            vi[2*j]   = q.y * RS2f + vi[2*j]   * sgn;
            vr[2*j+1] = q.z * RS2f + vr[2*j+1] * sgn;
            vi[2*j+1] = q.w * RS2f + vi[2*j+1] * sgn;
        }
    }
}

// ==================================================================
// 12-qubit circuit — EXACT R5/R8/R12/R15 structure (77-80us, frozen).
// ==================================================================
__global__ __launch_bounds__(256) void circuit_sa(const float* __restrict__ com,
                                                  const float* __restrict__ xf,
                                                  const float* __restrict__ qp,
                                                  float* __restrict__ out) {
    __shared__ float xbuf[8192];         // 32 KB exchange buffer
    __shared__ float ang[2048];          // 8 KB: com row, later xf row
    const int tid = threadIdx.x, lane = tid & 63, waveId = tid >> 6;
    const int b = blockIdx.x;
    if (tid < 128) ((float4*)ang)[tid] = ((const float4*)(com + b * 512))[tid];
    __syncthreads();
    float vr[16], vi[16];
    #pragma unroll
    for (int e = 0; e < 16; ++e) { vr[e] = 0.0f; vi[e] = 0.0f; }
    const float K9 = 0.044194173824159216f;   // 2^-4.5
    #pragma unroll
    for (int m = 0; m < 4; ++m) {
        int j = (lane << 3) | ((waveId & 1) << 2) | m;
        int rj = (int)(__brev((unsigned)j) >> 23);
        float s, c;
        sincosf(0.5f * ang[rj], &s, &c);
        vr[m << 2] = K9 * ((waveId & 2) ? s : c);
    }
    #pragma unroll 1
    for (int l = 0; l < 2; ++l) {
        { CMat M = mk_rot(qp, l, 0);  rot_wire<0 >(vr, vi, xbuf, waveId, lane, M); }
        { CMat M = mk_rot(qp, l, 1);  rot_wire<1 >(vr, vi, xbuf, waveId, lane, M); }
        { CMat M = mk_rot(qp, l, 2);  rot_wire<2 >(vr, vi, xbuf, waveId, lane, M); }
        { CMat M = mk_rot(qp, l, 3);  rot_wire<3 >(vr, vi, xbuf, waveId, lane, M); }
        { CMat M = mk_rot(qp, l, 4);  rot_wire<4 >(vr, vi, xbuf, waveId, lane, M); }
        { CMat M = mk_rot(qp, l, 5);  rot_wire<5 >(vr, vi, xbuf, waveId, lane, M); }
        { CMat M = mk_rot(qp, l, 6);  rot_wire<6 >(vr, vi, xbuf, waveId, lane, M); }
        { CMat M = mk_rot(qp, l, 7);  rot_wire<7 >(vr, vi, xbuf, waveId, lane, M); }
        { CMat M = mk_rot(qp, l, 8);  rot_wire<8 >(vr, vi, xbuf, waveId, lane, M); }
        { CMat M = mk_rot(qp, l, 9);  rot_wire<9 >(vr, vi, xbuf, waveId, lane, M); }
        { CMat M = mk_rot(qp, l, 10); rot_wire<10>(vr, vi, xbuf, waveId, lane, M); }
        { CMat M = mk_rot(qp, l, 11); rot_wire<11>(vr, vi, xbuf, waveId, lane, M); }
        if (l == 0) {                 // r = 1
            int j = lane;
            j ^= (j & 2)  ? 1  : 0;           // C(5,6)
            j ^= (j & 4)  ? 2  : 0;           // C(4,5)
            j ^= (j & 8)  ? 4  : 0;           // C(3,4)
            j ^= (j & 16) ? 8  : 0;           // C(2,3)
            j ^= (j & 32) ? 16 : 0;           // C(1,2)
            j ^= (waveId & 2) ? 32 : 0;       // C(0,1)
            shfl_perm(vr, vi, j);
            cnot<6,7>(vr,vi,xbuf,waveId,lane);   cnot<7,8>(vr,vi,xbuf,waveId,lane);
            cnot<8,9>(vr,vi,xbuf,waveId,lane);   cnot<9,10>(vr,vi,xbuf,waveId,lane);
            cnot<10,11>(vr,vi,xbuf,waveId,lane); cnot<11,0>(vr,vi,xbuf,waveId,lane);
        } else {                      // r = 2
            int j = lane;
            j ^= (j & 4)  ? 1  : 0;           // C(4,6)
            j ^= (j & 8)  ? 2  : 0;           // C(3,5)
            j ^= (j & 16) ? 4  : 0;           // C(2,4)
            j ^= (j & 32) ? 8  : 0;           // C(1,3)
            j ^= (waveId & 2) ? 16 : 0;       // C(0,2)
            shfl_perm(vr, vi, j);
            cnot<5,7>(vr,vi,xbuf,waveId,lane);   cnot<6,8>(vr,vi,xbuf,waveId,lane);
            cnot<7,9>(vr,vi,xbuf,waveId,lane);   cnot<8,10>(vr,vi,xbuf,waveId,lane);
            cnot<9,11>(vr,vi,xbuf,waveId,lane);  cnot<10,0>(vr,vi,xbuf,waveId,lane);
            cnot<11,1>(vr,vi,xbuf,waveId,lane);
        }
    }
    h_wire<1>(vr,vi,xbuf,waveId,lane);  h_wire<2>(vr,vi,xbuf,waveId,lane);
    h_wire<3>(vr,vi,xbuf,waveId,lane);  h_wire<4>(vr,vi,xbuf,waveId,lane);
    h_wire<5>(vr,vi,xbuf,waveId,lane);  h_wire<6>(vr,vi,xbuf,waveId,lane);
    h_wire<7>(vr,vi,xbuf,waveId,lane);  h_wire<8>(vr,vi,xbuf,waveId,lane);
    h_wire<9>(vr,vi,xbuf,waveId,lane);  h_wire<10>(vr,vi,xbuf,waveId,lane);
    h_wire<11>(vr,vi,xbuf,waveId,lane);
    {
        const float4* x4 = (const float4*)(xf + b * 2048);
        ((float4*)ang)[tid]       = x4[tid];
        ((float4*)ang)[tid + 256] = x4[tid + 256];
    }
    __syncthreads();
    exch_put(xbuf, (waveId << 6) + lane, vr, vi);
    {
        const float4* p = (const float4*)xbuf;
        const int ps = ((waveId ^ 2) << 6) + lane;
        const bool hi = waveId & 2;
        float acc = 0.0f;
        #pragma unroll
        for (int j = 0; j < 8; ++j) {
            float4 q = p[(j << 8) + ps];
            #pragma unroll
            for (int h = 0; h < 2; ++h) {
                const int e = 2*j + h;
                const float prr = h ? q.z : q.x;
                const float pii = h ? q.w : q.y;
                int v = (lane << 5) | ((waveId & 1) << 4) | e;
                int rv = (int)(__brev((unsigned)v) >> 21);
                float s, c;
                sincosf(0.5f * ang[rv], &s, &c);
                float nr = hi ? (s*prr + c*vr[e]) : (c*vr[e] - s*prr);
                float ni = hi ? (s*pii + c*vi[e]) : (c*vi[e] - s*pii);
                acc += nr*nr + ni*ni;
            }
        }
        if (!hi) acc = -acc;
        #pragma unroll
        for (int off = 32; off > 0; off >>= 1) acc += __shfl_down(acc, off, 64);
        __syncthreads();
        if (lane == 0) xbuf[waveId] = acc;
        __syncthreads();
        if (tid == 0) out[b] = xbuf[0] + xbuf[1] + xbuf[2] + xbuf[3];
    }
}

extern "C" void kernel_launch(void* const* d_in, const int* in_sizes, int n_in,
                              void* d_out, int out_size, void* d_ws, size_t ws_size,
                              hipStream_t stream) {
    const float* x    = (const float*)d_in[0];   // (1024,2048)
    const float* W    = (const float*)d_in[1];   // (512,2048)
    const float* bias = (const float*)d_in[2];   // (512,)
    const float* qp   = (const float*)d_in[3];   // (2,12,3)
    float* out = (float*)d_out;                  // (1024,)

    const size_t SLAB = 2097152;                 // 2 MB per P slab
    float* P = (float*)d_ws;
    if (ws_size >= 2 * SLAB) {
        int SK = 2;
        if      (ws_size >= 8 * SLAB) SK = 8;    // 1024 blocks = 4/CU
        else if (ws_size >= 4 * SLAB) SK = 4;
        dim3 g(16, 8, SK);                       // 64x64 tiles, split-K
        gemm_fused<<<g, 256, 0, stream>>>(x, W, P, 32 / SK);   // nch = 2048/64/SK
        reduce_kernel<<<2048, 256, 0, stream>>>(P, bias, SK);
        circuit_sa<<<1024, 256, 0, stream>>>(P, x, qp, out);
    } else {
        dim3 g(16, 16);
        gemm_f32<<<g, 256, 0, stream>>>(x, W, P);
        reduce_kernel<<<2048, 256, 0, stream>>>(P, bias, 1);
        circuit_sa<<<1024, 256, 0, stream>>>(P, x, qp, out);
    }
}